// Round 4
// baseline (7307.581 us; speedup 1.0000x reference)
//
#include <hip/hip_runtime.h>
#include <hip/hip_bf16.h>

#define Bn 64
#define Tn 1024
#define In 64
#define Dn 256

typedef short bf16x8 __attribute__((ext_vector_type(8)));
typedef unsigned short u16x8 __attribute__((ext_vector_type(8)));
typedef unsigned short u16x4 __attribute__((ext_vector_type(4)));
typedef float f32x4 __attribute__((ext_vector_type(4)));

__device__ __forceinline__ unsigned short f2bf(float f){
  unsigned u = __float_as_uint(f);
  u += 0x7fffu + ((u >> 16) & 1u);       // RNE
  return (unsigned short)(u >> 16);
}
__device__ __forceinline__ float sig_(float x){ return 1.f / (1.f + __expf(-x)); }
__device__ __forceinline__ float tanh_(float x){ float e = __expf(2.f * x); return 1.f - 2.f / (e + 1.f); }

__device__ __forceinline__ bf16x8 pack8(const float* f){
  bf16x8 r;
  #pragma unroll
  for (int i = 0; i < 8; ++i) r[i] = (short)f2bf(f[i]);
  return r;
}

// ---------------------------------------------------------------------------
// LSTM scan v4: 8 WGs x 512 threads = 4 chains (16 batches each) x 2 WGs
// (128 dims each, 8 waves x 16 dims). Wave slot W = (g>>2)*8 + waveid owns
// dims [W*16, W*16+16) x 4 gates for the chain's 16 batches; weights live in
// registers as bf16 MFMA A-fragments (identical per-wave math to v3).
// Sync: per-WG tag after {h-store, vmcnt(0), barrier}; consumers poll the 2
// chain tags with RELAXED loads (no per-iteration L2 maintenance) and read h
// via L2-bypassing relaxed atomics. Max-coupling per step: 2 WGs, and each CU
// serves exactly one chain (no cross-chain resource coupling).
// ---------------------------------------------------------------------------
__global__ __launch_bounds__(512, 2) void lstm_scan_kernel(
    const float* __restrict__ x, const float* __restrict__ Wih,
    const float* __restrict__ Whh, const float* __restrict__ bih,
    const float* __restrict__ bhh, unsigned short* __restrict__ Hbf,
    unsigned short* __restrict__ hx, unsigned int* __restrict__ tags)
{
  const int g = blockIdx.x;        // 0..7
  const int v = g & 3;             // chain (batch-group)
  const int s = g >> 2;            // dim half 0..1
  const int tid = threadIdx.x;
  const int u = tid >> 6;          // wave 0..7
  const int l = tid & 63;
  const int lr = l & 15, lg = l >> 4;
  const int W = s * 8 + u;         // dim slot 0..15 -> dims [W*16, W*16+16)

  // --- W fragments (A operand), bf16, register-resident ---
  // A-frag: row = l&15, k = lg*8..+8. Tile mt covers dims {d: d%4==mt} of the
  // slot; A-row order (dim_local*4+gate) makes each lane's C regs = 4 gates
  // of one dim for one batch.
  bf16x8 wfr[4][10];
  {
    const int gate = lr & 3, dimx = lr >> 2;
    #pragma unroll
    for (int mt = 0; mt < 4; ++mt){
      const int dim = W * 16 + dimx * 4 + mt;
      const int row = gate * Dn + dim;
      #pragma unroll
      for (int kt = 0; kt < 8; ++kt){
        float tmp[8];
        *(float4*)&tmp[0] = *(const float4*)&Whh[row * Dn + kt * 32 + lg * 8];
        *(float4*)&tmp[4] = *(const float4*)&Whh[row * Dn + kt * 32 + lg * 8 + 4];
        wfr[mt][kt] = pack8(tmp);
      }
      #pragma unroll
      for (int xt = 0; xt < 2; ++xt){
        float tmp[8];
        *(float4*)&tmp[0] = *(const float4*)&Wih[row * In + xt * 32 + lg * 8];
        *(float4*)&tmp[4] = *(const float4*)&Wih[row * In + xt * 32 + lg * 8 + 4];
        wfr[mt][8 + xt] = pack8(tmp);
      }
    }
  }
  // biases in C layout: lane holds (gate=i, dim = W*16 + lg*4 + mt)
  float bias[4][4];
  #pragma unroll
  for (int mt = 0; mt < 4; ++mt){
    const int dim = W * 16 + lg * 4 + mt;
    #pragma unroll
    for (int i = 0; i < 4; ++i)
      bias[mt][i] = bih[i * Dn + dim] + bhh[i * Dn + dim];
  }

  float cst[4] = {0.f, 0.f, 0.f, 0.f};
  const int b = v * 16 + lr;               // lane's batch
  const int dim0 = W * 16 + lg * 4;        // lane's first output dim

  // x prefetch double-buffer (registers, fp32)
  float xc[16], xn[16];
  {
    const float* xr = x + (size_t)(b * Tn) * In;
    #pragma unroll
    for (int xt = 0; xt < 2; ++xt)
      #pragma unroll
      for (int q = 0; q < 2; ++q)
        *(float4*)&xc[xt * 8 + q * 4] = *(const float4*)&xr[xt * 32 + lg * 8 + q * 4];
  }

  for (int t = 0; t < Tn; ++t){
    bf16x8 xb0 = pack8(&xc[0]);
    bf16x8 xb1 = pack8(&xc[8]);

    // init acc with bias, fold in x contribution before waiting on peers
    f32x4 acc[4];
    #pragma unroll
    for (int mt = 0; mt < 4; ++mt){
      f32x4 a = {bias[mt][0], bias[mt][1], bias[mt][2], bias[mt][3]};
      a = __builtin_amdgcn_mfma_f32_16x16x32_bf16(wfr[mt][8], xb0, a, 0, 0, 0);
      a = __builtin_amdgcn_mfma_f32_16x16x32_bf16(wfr[mt][9], xb1, a, 0, 0, 0);
      acc[mt] = a;
    }

    // issue x(t+1) prefetch BEFORE the poll: drains during the wait
    {
      const int tn = (t + 1 < Tn) ? t + 1 : t;
      const float* xr = x + (size_t)(b * Tn + tn) * In;
      #pragma unroll
      for (int xt = 0; xt < 2; ++xt)
        #pragma unroll
        for (int q = 0; q < 2; ++q)
          *(float4*)&xn[xt * 8 + q * 4] = *(const float4*)&xr[xt * 32 + lg * 8 + q * 4];
    }

    if (t > 0){
      // wait for this chain's 2 WG tags (parity (t-1)&1). RELAXED polls: no
      // L2 maintenance per iteration; h data loads below bypass L1/L2 so
      // stale caches are impossible, and tag@L3 => h@L3 (producer ordering).
      const unsigned want = (unsigned)t;
      const unsigned int* tg = tags + ((t - 1) & 1) * 16;
      int ok;
      do {
        unsigned tv = want;
        if (l < 2)
          tv = __hip_atomic_load(&tg[v + l * 4], __ATOMIC_RELAXED, __HIP_MEMORY_SCOPE_AGENT);
        ok = __all((int)(tv >= want));
        if (!ok) __builtin_amdgcn_s_sleep(1);
      } while (!ok);
      asm volatile("" ::: "memory");   // compiler fence: keep h loads below

      // load h B-fragments directly from the exchange buffer (L1/L2-bypass)
      const unsigned long long* hsrc =
          (const unsigned long long*)(hx + (size_t)((t - 1) & 1) * Bn * Dn);
      unsigned long long hl[16];
      #pragma unroll
      for (int kt = 0; kt < 8; ++kt){
        const int qi = (b * Dn + kt * 32 + lg * 8) >> 2;   // u64 index
        hl[2 * kt]     = __hip_atomic_load(&hsrc[qi],     __ATOMIC_RELAXED, __HIP_MEMORY_SCOPE_AGENT);
        hl[2 * kt + 1] = __hip_atomic_load(&hsrc[qi + 1], __ATOMIC_RELAXED, __HIP_MEMORY_SCOPE_AGENT);
      }
      #pragma unroll
      for (int kt = 0; kt < 8; ++kt){
        union { unsigned long long q[2]; bf16x8 f; } un;
        un.q[0] = hl[2 * kt]; un.q[1] = hl[2 * kt + 1];
        #pragma unroll
        for (int mt = 0; mt < 4; ++mt)
          acc[mt] = __builtin_amdgcn_mfma_f32_16x16x32_bf16(wfr[mt][kt], un.f, acc[mt], 0, 0, 0);
      }
    }

    // elementwise: lane holds 4 gates of dim (dim0+mt) for batch b
    unsigned long long hq = 0;
    #pragma unroll
    for (int mt = 0; mt < 4; ++mt){
      const float ig = sig_(acc[mt][0]);
      const float fg = sig_(acc[mt][1]);
      const float gg = tanh_(acc[mt][2]);
      const float og = sig_(acc[mt][3]);
      const float c = fg * cst[mt] + ig * gg;
      cst[mt] = c;
      const float h = og * tanh_(c);
      hq |= (unsigned long long)f2bf(h) << (16 * mt);
    }
    // publish h (8B, 4 consecutive dims), L2-bypassing
    unsigned long long* hdst = (unsigned long long*)(hx + (size_t)(t & 1) * Bn * Dn);
    __hip_atomic_store(&hdst[(b * Dn + dim0) >> 2], hq, __ATOMIC_RELAXED, __HIP_MEMORY_SCOPE_AGENT);
    // order: h stores (all waves) acked at coherence point -> WG tag
    asm volatile("s_waitcnt vmcnt(0)" ::: "memory");
    __syncthreads();
    if (tid == 0)
      __hip_atomic_store(&tags[(t & 1) * 16 + g], (unsigned)(t + 1),
                         __ATOMIC_RELAXED, __HIP_MEMORY_SCOPE_AGENT);
    // history copy for attn/mlp: off the critical path (after the tag)
    *(unsigned long long*)&Hbf[(size_t)(b * Tn + t) * Dn + dim0] = hq;
    #pragma unroll
    for (int q = 0; q < 16; ++q) xc[q] = xn[q];
  }
}

// ---------------------------------------------------------------------------
// Flash attention, Q=K=V=H (bf16), unscaled, causal. One WG per (b, 64-row qtile).
// ---------------------------------------------------------------------------
__global__ __launch_bounds__(256, 1) void attn_kernel(
    const unsigned short* __restrict__ Hbf, unsigned short* __restrict__ ctxbf)
{
  const int bid = blockIdx.x;
  const int b = bid >> 4, qt = bid & 15;
  const int q0 = qt * 64;
  const int tid = threadIdx.x;
  const int w = tid >> 6, l = tid & 63;
  const int lr = l & 15, lg = l >> 4;

  __shared__ unsigned short Qs[64 * 256];
  __shared__ unsigned short Ks[64 * 256];
  __shared__ unsigned short Vt[256 * 64];   // transposed: [d][s]
  __shared__ unsigned short Ps[64 * 64];

  {
    const int r = tid >> 2, cs = (tid & 3) * 64;
    #pragma unroll
    for (int jj = 0; jj < 8; ++jj){
      const int c = cs + jj * 8;
      u16x8 v = *(const u16x8*)&Hbf[(b * Tn + q0 + r) * Dn + c];
      *(u16x8*)((char*)Qs + (((r * 256 + c) * 2) ^ ((r & 7) << 4))) = v;
    }
  }
  __syncthreads();
  bf16x8 qf[8];
  #pragma unroll
  for (int kc = 0; kc < 8; ++kc){
    const int r = w * 16 + lr, c = kc * 32 + lg * 8;
    qf[kc] = *(const bf16x8*)((const char*)Qs + (((r * 256 + c) * 2) ^ ((r & 7) << 4)));
  }

  float m_i[4], l_i[4];
  f32x4 o_acc[16];
  #pragma unroll
  for (int i = 0; i < 4; ++i){ m_i[i] = -__builtin_inff(); l_i[i] = 0.f; }
  #pragma unroll
  for (int n = 0; n < 16; ++n) o_acc[n] = (f32x4){0.f, 0.f, 0.f, 0.f};

  for (int kt = 0; kt <= qt; ++kt){
    const int s0 = kt * 64;
    __syncthreads();    // previous-iteration K/Vt consumers done
    {
      const int r = tid >> 2, cs = (tid & 3) * 64;
      #pragma unroll
      for (int jj = 0; jj < 8; ++jj){
        const int c = cs + jj * 8;
        u16x8 v = *(const u16x8*)&Hbf[(b * Tn + s0 + r) * Dn + c];
        *(u16x8*)((char*)Ks + (((r * 256 + c) * 2) ^ ((r & 7) << 4))) = v;
      }
    }
    {
      const int s = tid & 63, db = tid >> 6;
      #pragma unroll
      for (int jj = 0; jj < 8; ++jj){
        const int d0 = db * 64 + jj * 8;
        u16x8 v = *(const u16x8*)&Hbf[(b * Tn + s0 + s) * Dn + d0];
        #pragma unroll
        for (int e = 0; e < 8; ++e){
          const int d = d0 + e;
          *(unsigned short*)((char*)Vt + (((d * 64 + s) * 2) ^ ((d & 7) << 4))) = (unsigned short)v[e];
        }
      }
    }
    __syncthreads();
    // S = Q K^T for this wave's 16 q-rows
    f32x4 sacc[4];
    #pragma unroll
    for (int n = 0; n < 4; ++n) sacc[n] = (f32x4){0.f, 0.f, 0.f, 0.f};
    #pragma unroll
    for (int kc = 0; kc < 8; ++kc){
      #pragma unroll
      for (int n = 0; n < 4; ++n){
        const int r = n * 16 + lr, c = kc * 32 + lg * 8;
        bf16x8 kfr = *(const bf16x8*)((const char*)Ks + (((r * 256 + c) * 2) ^ ((r & 7) << 4)));
        sacc[n] = __builtin_amdgcn_mfma_f32_16x16x32_bf16(qf[kc], kfr, sacc[n], 0, 0, 0);
      }
    }
    if (kt == qt){
      #pragma unroll
      for (int n = 0; n < 4; ++n)
        #pragma unroll
        for (int i = 0; i < 4; ++i){
          const int scol = s0 + n * 16 + lr;
          const int qrow = q0 + w * 16 + lg * 4 + i;
          if (scol > qrow) sacc[n][i] = -__builtin_inff();
        }
    }
    float rmax[4], alpha[4], rsum[4];
    #pragma unroll
    for (int i = 0; i < 4; ++i){
      float v = fmaxf(fmaxf(sacc[0][i], sacc[1][i]), fmaxf(sacc[2][i], sacc[3][i]));
      v = fmaxf(v, __shfl_xor(v, 1));
      v = fmaxf(v, __shfl_xor(v, 2));
      v = fmaxf(v, __shfl_xor(v, 4));
      v = fmaxf(v, __shfl_xor(v, 8));
      rmax[i] = v;
    }
    #pragma unroll
    for (int i = 0; i < 4; ++i){
      const float mn = fmaxf(m_i[i], rmax[i]);
      alpha[i] = __expf(m_i[i] - mn);
      m_i[i] = mn;
      rsum[i] = 0.f;
    }
    #pragma unroll
    for (int n = 0; n < 4; ++n){
      #pragma unroll
      for (int i = 0; i < 4; ++i){
        const float pv = __expf(sacc[n][i] - m_i[i]);   // exp(-inf)=0 handles mask
        rsum[i] += pv;
        const int r = w * 16 + lg * 4 + i, c = n * 16 + lr;
        *(unsigned short*)((char*)Ps + (((r * 64 + c) * 2) ^ ((r & 7) << 4))) = f2bf(pv);
      }
    }
    #pragma unroll
    for (int i = 0; i < 4; ++i){
      float v = rsum[i];
      v += __shfl_xor(v, 1);
      v += __shfl_xor(v, 2);
      v += __shfl_xor(v, 4);
      v += __shfl_xor(v, 8);
      l_i[i] = l_i[i] * alpha[i] + v;
    }
    #pragma unroll
    for (int n = 0; n < 16; ++n)
      #pragma unroll
      for (int i = 0; i < 4; ++i) o_acc[n][i] *= alpha[i];
    // PV: each wave reads only its own P rows (same-wave LDS dep, compiler waits lgkmcnt)
    #pragma unroll
    for (int kc = 0; kc < 2; ++kc){
      const int r = w * 16 + lr, c = kc * 32 + lg * 8;
      bf16x8 pfr = *(const bf16x8*)((const char*)Ps + (((r * 64 + c) * 2) ^ ((r & 7) << 4)));
      #pragma unroll
      for (int n = 0; n < 16; ++n){
        const int vr = n * 16 + lr, vc = kc * 32 + lg * 8;
        bf16x8 vfr = *(const bf16x8*)((const char*)Vt + (((vr * 64 + vc) * 2) ^ ((vr & 7) << 4)));
        o_acc[n] = __builtin_amdgcn_mfma_f32_16x16x32_bf16(pfr, vfr, o_acc[n], 0, 0, 0);
      }
    }
  }
  #pragma unroll
  for (int n = 0; n < 16; ++n)
    #pragma unroll
    for (int i = 0; i < 4; ++i){
      const float v = o_acc[n][i] / l_i[i];
      const int q = q0 + w * 16 + lg * 4 + i;
      const int d = n * 16 + lr;
      ctxbf[(b * Tn + q) * Dn + d] = f2bf(v);
    }
}

// ---------------------------------------------------------------------------
// MLP: out = relu([H|ctx] @ W1^T + b1) @ W2^T + b2, fused per 64-row M tile.
// ---------------------------------------------------------------------------
__global__ __launch_bounds__(256, 1) void mlp_kernel(
    const unsigned short* __restrict__ Hbf, const unsigned short* __restrict__ ctxbf,
    const float* __restrict__ W1, const float* __restrict__ b1,
    const float* __restrict__ W2, const float* __restrict__ b2,
    float* __restrict__ out)
{
  const int m0 = blockIdx.x * 64;
  const int tid = threadIdx.x;
  const int w = tid >> 6, l = tid & 63;
  const int lr = l & 15, lg = l >> 4;

  __shared__ unsigned short As[64 * 512];
  __shared__ unsigned short Ws[64 * 512];

  {
    const int r = tid >> 2, cs = (tid & 3) * 128;
    #pragma unroll
    for (int jj = 0; jj < 16; ++jj){
      const int c = cs + jj * 8;
      u16x8 v;
      if (c < 256) v = *(const u16x8*)&Hbf[(m0 + r) * Dn + c];
      else         v = *(const u16x8*)&ctxbf[(m0 + r) * Dn + (c - 256)];
      *(u16x8*)((char*)As + (((r * 512 + c) * 2) ^ ((r & 7) << 4))) = v;
    }
  }
  f32x4 hacc[16];
  #pragma unroll
  for (int n = 0; n < 16; ++n) hacc[n] = (f32x4){0.f, 0.f, 0.f, 0.f};

  for (int nb = 0; nb < 4; ++nb){
    __syncthreads();
    {
      const int r = tid >> 2, cs = (tid & 3) * 128;
      #pragma unroll
      for (int jj = 0; jj < 32; ++jj){
        const int c = cs + jj * 4;
        const float4 v = *(const float4*)&W1[(nb * 64 + r) * 512 + c];
        u16x4 pk = { f2bf(v.x), f2bf(v.y), f2bf(v.z), f2bf(v.w) };
        *(u16x4*)((char*)Ws + (((r * 512 + c) * 2) ^ ((r & 7) << 4))) = pk;
      }
    }
    __syncthreads();
    #pragma unroll
    for (int kc = 0; kc < 16; ++kc){
      const int ar = w * 16 + lr, ac = kc * 32 + lg * 8;
      bf16x8 af = *(const bf16x8*)((const char*)As + (((ar * 512 + ac) * 2) ^ ((ar & 7) << 4)));
      #pragma unroll
      for (int n = 0; n < 4; ++n){
        const int br = n * 16 + lr;
        bf16x8 bf = *(const bf16x8*)((const char*)Ws + (((br * 512 + ac) * 2) ^ ((br & 7) << 4)));
        hacc[nb * 4 + n] = __builtin_amdgcn_mfma_f32_16x16x32_bf16(af, bf, hacc[nb * 4 + n], 0, 0, 0);
      }
    }
  }
  __syncthreads();
  // relu + b1 -> hid (bf16) into As as [64][256]
  #pragma unroll
  for (int nn = 0; nn < 16; ++nn){
    const int col = (nn >> 2) * 64 + (nn & 3) * 16 + lr;
    const float bv = b1[col];
    #pragma unroll
    for (int i = 0; i < 4; ++i){
      float v = hacc[nn][i] + bv;
      v = v > 0.f ? v : 0.f;
      const int r = w * 16 + lg * 4 + i;
      *(unsigned short*)((char*)As + (((r * 256 + col) * 2) ^ ((r & 7) << 4))) = f2bf(v);
    }
  }
  {
    const int r = tid >> 2, cs = (tid & 3) * 64;
    #pragma unroll
    for (int jj = 0; jj < 16; ++jj){
      const int c = cs + jj * 4;
      const float4 v = *(const float4*)&W2[r * 256 + c];
      u16x4 pk = { f2bf(v.x), f2bf(v.y), f2bf(v.z), f2bf(v.w) };
      *(u16x4*)((char*)Ws + (((r * 256 + c) * 2) ^ ((r & 7) << 4))) = pk;
    }
  }
  __syncthreads();
  f32x4 oacc[4];
  #pragma unroll
  for (int n = 0; n < 4; ++n) oacc[n] = (f32x4){0.f, 0.f, 0.f, 0.f};
  #pragma unroll
  for (int kc = 0; kc < 8; ++kc){
    const int ar = w * 16 + lr, ac = kc * 32 + lg * 8;
    bf16x8 af = *(const bf16x8*)((const char*)As + (((ar * 256 + ac) * 2) ^ ((ar & 7) << 4)));
    #pragma unroll
    for (int n = 0; n < 4; ++n){
      const int br = n * 16 + lr;
      bf16x8 bf = *(const bf16x8*)((const char*)Ws + (((br * 256 + ac) * 2) ^ ((br & 7) << 4)));
      oacc[n] = __builtin_amdgcn_mfma_f32_16x16x32_bf16(af, bf, oacc[n], 0, 0, 0);
    }
  }
  #pragma unroll
  for (int n = 0; n < 4; ++n)
    #pragma unroll
    for (int i = 0; i < 4; ++i){
      const int ii = n * 16 + lr;
      const int m = m0 + w * 16 + lg * 4 + i;
      out[m * In + ii] = oacc[n][i] + b2[ii];
    }
}

extern "C" void kernel_launch(void* const* d_in, const int* in_sizes, int n_in,
                              void* d_out, int out_size, void* d_ws, size_t ws_size,
                              hipStream_t stream)
{
  (void)in_sizes; (void)n_in; (void)out_size; (void)ws_size;
  const float* x   = (const float*)d_in[0];
  const float* Wih = (const float*)d_in[1];
  const float* Whh = (const float*)d_in[2];
  const float* bih = (const float*)d_in[3];
  const float* bhh = (const float*)d_in[4];
  const float* W1  = (const float*)d_in[5];
  const float* b1  = (const float*)d_in[6];
  const float* W2  = (const float*)d_in[7];
  const float* b2  = (const float*)d_in[8];
  float* out = (float*)d_out;

  char* ws = (char*)d_ws;
  unsigned short* Hbf   = (unsigned short*)ws;                              // 32 MB
  unsigned short* ctxbf = (unsigned short*)(ws + (size_t)32 * 1024 * 1024); // 32 MB
  unsigned short* hx    = (unsigned short*)(ws + (size_t)64 * 1024 * 1024); // 64 KB
  unsigned int*   tags  = (unsigned int*)(ws + (size_t)64 * 1024 * 1024 + 128 * 1024); // 128 B

  hipMemsetAsync(tags, 0, 2 * 16 * sizeof(unsigned int), stream);
  lstm_scan_kernel<<<8, 512, 0, stream>>>(x, Wih, Whh, bih, bhh, Hbf, hx, tags);
  attn_kernel<<<Bn * 16, 256, 0, stream>>>(Hbf, ctxbf);
  mlp_kernel<<<(Bn * Tn) / 64, 256, 0, stream>>>(Hbf, ctxbf, W1, b1, W2, b2, out);
}

// Round 5
// 4973.601 us; speedup vs baseline: 1.4693x; 1.4693x over previous
//
#include <hip/hip_runtime.h>
#include <hip/hip_bf16.h>

#define Bn 64
#define Tn 1024
#define In 64
#define Dn 256

typedef short bf16x8 __attribute__((ext_vector_type(8)));
typedef unsigned short u16x8 __attribute__((ext_vector_type(8)));
typedef unsigned short u16x4 __attribute__((ext_vector_type(4)));
typedef float f32x4 __attribute__((ext_vector_type(4)));

__device__ __forceinline__ unsigned short f2bf(float f){
  unsigned u = __float_as_uint(f);
  u += 0x7fffu + ((u >> 16) & 1u);       // RNE
  return (unsigned short)(u >> 16);
}
__device__ __forceinline__ float sig_(float x){ return 1.f / (1.f + __expf(-x)); }
__device__ __forceinline__ float tanh_(float x){ float e = __expf(2.f * x); return 1.f - 2.f / (e + 1.f); }

__device__ __forceinline__ bf16x8 pack8(const float* f){
  bf16x8 r;
  #pragma unroll
  for (int i = 0; i < 8; ++i) r[i] = (short)f2bf(f[i]);
  return r;
}

// ---------------------------------------------------------------------------
// LSTM scan v5 = v3 structure + v4 relaxed protocol.
// 16 WGs x 4 waves. WG w owns dims [w*16, w*16+16) x 4 gates; wave v owns
// batches [v*16, v*16+16) (= chain v). Weights live in registers as bf16 MFMA
// A-fragments (196 VGPR, 1 wave/SIMD, proven no-spill codegen).
// Protocol: RELAXED tag polls (no L2 maintenance per iteration — the v3
// acquire-poll invalidated L2 every iteration, forcing 200MB of x re-fetch),
// producer orders h-store -> tag with explicit s_waitcnt vmcnt(0), relaxed
// tag store. h data moves via L1/L2-bypassing relaxed atomics (coherence
// point), so no cache can go stale. Correctness of this scheme was validated
// in round 4 (absmax 0.00195).
// ---------------------------------------------------------------------------
__global__ __launch_bounds__(256, 1) void lstm_scan_kernel(
    const float* __restrict__ x, const float* __restrict__ Wih,
    const float* __restrict__ Whh, const float* __restrict__ bih,
    const float* __restrict__ bhh, unsigned short* __restrict__ Hbf,
    unsigned short* __restrict__ hx, unsigned int* __restrict__ tags)
{
  const int w = blockIdx.x;        // dim block 0..15
  const int tid = threadIdx.x;
  const int v = tid >> 6;          // wave 0..3 -> chain v, batches v*16..+16
  const int l = tid & 63;
  const int lr = l & 15, lg = l >> 4;

  // --- W fragments (A operand), bf16, register-resident ---
  // A-frag: row = l&15, k = lg*8..+8. Tile mt covers dims {d: d%4==mt} of
  // this WG; A-row order (dim_local*4+gate) makes each lane's C regs = the
  // 4 gates of one dim for one batch.
  bf16x8 wfr[4][10];
  {
    const int gate = lr & 3, dimx = lr >> 2;
    #pragma unroll
    for (int mt = 0; mt < 4; ++mt){
      const int dim = w * 16 + dimx * 4 + mt;
      const int row = gate * Dn + dim;
      #pragma unroll
      for (int kt = 0; kt < 8; ++kt){
        float tmp[8];
        *(float4*)&tmp[0] = *(const float4*)&Whh[row * Dn + kt * 32 + lg * 8];
        *(float4*)&tmp[4] = *(const float4*)&Whh[row * Dn + kt * 32 + lg * 8 + 4];
        wfr[mt][kt] = pack8(tmp);
      }
      #pragma unroll
      for (int xt = 0; xt < 2; ++xt){
        float tmp[8];
        *(float4*)&tmp[0] = *(const float4*)&Wih[row * In + xt * 32 + lg * 8];
        *(float4*)&tmp[4] = *(const float4*)&Wih[row * In + xt * 32 + lg * 8 + 4];
        wfr[mt][8 + xt] = pack8(tmp);
      }
    }
  }
  // biases in C layout: lane holds (gate=i, dim = w*16 + lg*4 + mt)
  float bias[4][4];
  #pragma unroll
  for (int mt = 0; mt < 4; ++mt){
    const int dim = w * 16 + lg * 4 + mt;
    #pragma unroll
    for (int i = 0; i < 4; ++i)
      bias[mt][i] = bih[i * Dn + dim] + bhh[i * Dn + dim];
  }

  float cst[4] = {0.f, 0.f, 0.f, 0.f};
  const int b = v * 16 + lr;               // lane's batch
  const int dim0 = w * 16 + lg * 4;        // lane's first output dim

  // x prefetch double-buffer (registers, fp32)
  float xc[16], xn[16];
  {
    const float* xr = x + (size_t)(b * Tn) * In;
    #pragma unroll
    for (int xt = 0; xt < 2; ++xt)
      #pragma unroll
      for (int q = 0; q < 2; ++q)
        *(float4*)&xc[xt * 8 + q * 4] = *(const float4*)&xr[xt * 32 + lg * 8 + q * 4];
  }

  for (int t = 0; t < Tn; ++t){
    bf16x8 xb0 = pack8(&xc[0]);
    bf16x8 xb1 = pack8(&xc[8]);

    // init acc with bias, fold in x contribution before waiting on peers
    f32x4 acc[4];
    #pragma unroll
    for (int mt = 0; mt < 4; ++mt){
      f32x4 a = {bias[mt][0], bias[mt][1], bias[mt][2], bias[mt][3]};
      a = __builtin_amdgcn_mfma_f32_16x16x32_bf16(wfr[mt][8], xb0, a, 0, 0, 0);
      a = __builtin_amdgcn_mfma_f32_16x16x32_bf16(wfr[mt][9], xb1, a, 0, 0, 0);
      acc[mt] = a;
    }

    // issue x(t+1) prefetch BEFORE the poll: drains during the wait
    {
      const int tn = (t + 1 < Tn) ? t + 1 : t;
      const float* xr = x + (size_t)(b * Tn + tn) * In;
      #pragma unroll
      for (int xt = 0; xt < 2; ++xt)
        #pragma unroll
        for (int q = 0; q < 2; ++q)
          *(float4*)&xn[xt * 8 + q * 4] = *(const float4*)&xr[xt * 32 + lg * 8 + q * 4];
    }

    if (t > 0){
      // wait for this chain's 16 WG tags (one 64B line), RELAXED polls:
      // no L2 maintenance per iteration.
      const unsigned want = (unsigned)t;
      const unsigned int* tg = tags + ((t - 1) & 1) * 64 + v * 16;
      int ok;
      do {
        unsigned tv = want;
        if (l < 16)
          tv = __hip_atomic_load(&tg[l], __ATOMIC_RELAXED, __HIP_MEMORY_SCOPE_AGENT);
        ok = __all((int)(tv >= want));
        if (!ok) __builtin_amdgcn_s_sleep(1);
      } while (!ok);
      asm volatile("" ::: "memory");   // compiler fence: keep h loads below

      // load h B-fragments directly from the exchange buffer (L1/L2-bypass)
      const unsigned long long* hsrc =
          (const unsigned long long*)(hx + (size_t)((t - 1) & 1) * Bn * Dn);
      unsigned long long hl[16];
      #pragma unroll
      for (int kt = 0; kt < 8; ++kt){
        const int qi = (b * Dn + kt * 32 + lg * 8) >> 2;   // u64 index
        hl[2 * kt]     = __hip_atomic_load(&hsrc[qi],     __ATOMIC_RELAXED, __HIP_MEMORY_SCOPE_AGENT);
        hl[2 * kt + 1] = __hip_atomic_load(&hsrc[qi + 1], __ATOMIC_RELAXED, __HIP_MEMORY_SCOPE_AGENT);
      }
      #pragma unroll
      for (int kt = 0; kt < 8; ++kt){
        union { unsigned long long q[2]; bf16x8 f; } un;
        un.q[0] = hl[2 * kt]; un.q[1] = hl[2 * kt + 1];
        #pragma unroll
        for (int mt = 0; mt < 4; ++mt)
          acc[mt] = __builtin_amdgcn_mfma_f32_16x16x32_bf16(wfr[mt][kt], un.f, acc[mt], 0, 0, 0);
      }
    }

    // elementwise: lane holds 4 gates of dim (dim0+mt) for batch b
    unsigned long long hq = 0;
    #pragma unroll
    for (int mt = 0; mt < 4; ++mt){
      const float ig = sig_(acc[mt][0]);
      const float fg = sig_(acc[mt][1]);
      const float gg = tanh_(acc[mt][2]);
      const float og = sig_(acc[mt][3]);
      const float c = fg * cst[mt] + ig * gg;
      cst[mt] = c;
      const float h = og * tanh_(c);
      hq |= (unsigned long long)f2bf(h) << (16 * mt);
    }
    // publish h (8B, 4 consecutive dims), coherence-point store
    unsigned long long* hdst = (unsigned long long*)(hx + (size_t)(t & 1) * Bn * Dn);
    __hip_atomic_store(&hdst[(b * Dn + dim0) >> 2], hq, __ATOMIC_RELAXED, __HIP_MEMORY_SCOPE_AGENT);
    // order: this wave's h store acked at coherence point -> tag store
    asm volatile("s_waitcnt vmcnt(0)" ::: "memory");
    if (l == 0)
      __hip_atomic_store(&tags[(t & 1) * 64 + v * 16 + w], (unsigned)(t + 1),
                         __ATOMIC_RELAXED, __HIP_MEMORY_SCOPE_AGENT);
    // history copy for attn/mlp: off the critical path (after the tag)
    *(unsigned long long*)&Hbf[(size_t)(b * Tn + t) * Dn + dim0] = hq;
    #pragma unroll
    for (int q = 0; q < 16; ++q) xc[q] = xn[q];
  }
}

// ---------------------------------------------------------------------------
// Flash attention, Q=K=V=H (bf16), unscaled, causal. One WG per (b, 64-row qtile).
// ---------------------------------------------------------------------------
__global__ __launch_bounds__(256, 1) void attn_kernel(
    const unsigned short* __restrict__ Hbf, unsigned short* __restrict__ ctxbf)
{
  const int bid = blockIdx.x;
  const int b = bid >> 4, qt = bid & 15;
  const int q0 = qt * 64;
  const int tid = threadIdx.x;
  const int w = tid >> 6, l = tid & 63;
  const int lr = l & 15, lg = l >> 4;

  __shared__ unsigned short Qs[64 * 256];
  __shared__ unsigned short Ks[64 * 256];
  __shared__ unsigned short Vt[256 * 64];   // transposed: [d][s]
  __shared__ unsigned short Ps[64 * 64];

  {
    const int r = tid >> 2, cs = (tid & 3) * 64;
    #pragma unroll
    for (int jj = 0; jj < 8; ++jj){
      const int c = cs + jj * 8;
      u16x8 v = *(const u16x8*)&Hbf[(b * Tn + q0 + r) * Dn + c];
      *(u16x8*)((char*)Qs + (((r * 256 + c) * 2) ^ ((r & 7) << 4))) = v;
    }
  }
  __syncthreads();
  bf16x8 qf[8];
  #pragma unroll
  for (int kc = 0; kc < 8; ++kc){
    const int r = w * 16 + lr, c = kc * 32 + lg * 8;
    qf[kc] = *(const bf16x8*)((const char*)Qs + (((r * 256 + c) * 2) ^ ((r & 7) << 4)));
  }

  float m_i[4], l_i[4];
  f32x4 o_acc[16];
  #pragma unroll
  for (int i = 0; i < 4; ++i){ m_i[i] = -__builtin_inff(); l_i[i] = 0.f; }
  #pragma unroll
  for (int n = 0; n < 16; ++n) o_acc[n] = (f32x4){0.f, 0.f, 0.f, 0.f};

  for (int kt = 0; kt <= qt; ++kt){
    const int s0 = kt * 64;
    __syncthreads();    // previous-iteration K/Vt consumers done
    {
      const int r = tid >> 2, cs = (tid & 3) * 64;
      #pragma unroll
      for (int jj = 0; jj < 8; ++jj){
        const int c = cs + jj * 8;
        u16x8 v = *(const u16x8*)&Hbf[(b * Tn + s0 + r) * Dn + c];
        *(u16x8*)((char*)Ks + (((r * 256 + c) * 2) ^ ((r & 7) << 4))) = v;
      }
    }
    {
      const int s = tid & 63, db = tid >> 6;
      #pragma unroll
      for (int jj = 0; jj < 8; ++jj){
        const int d0 = db * 64 + jj * 8;
        u16x8 v = *(const u16x8*)&Hbf[(b * Tn + s0 + s) * Dn + d0];
        #pragma unroll
        for (int e = 0; e < 8; ++e){
          const int d = d0 + e;
          *(unsigned short*)((char*)Vt + (((d * 64 + s) * 2) ^ ((d & 7) << 4))) = (unsigned short)v[e];
        }
      }
    }
    __syncthreads();
    // S = Q K^T for this wave's 16 q-rows
    f32x4 sacc[4];
    #pragma unroll
    for (int n = 0; n < 4; ++n) sacc[n] = (f32x4){0.f, 0.f, 0.f, 0.f};
    #pragma unroll
    for (int kc = 0; kc < 8; ++kc){
      #pragma unroll
      for (int n = 0; n < 4; ++n){
        const int r = n * 16 + lr, c = kc * 32 + lg * 8;
        bf16x8 kfr = *(const bf16x8*)((const char*)Ks + (((r * 256 + c) * 2) ^ ((r & 7) << 4)));
        sacc[n] = __builtin_amdgcn_mfma_f32_16x16x32_bf16(qf[kc], kfr, sacc[n], 0, 0, 0);
      }
    }
    if (kt == qt){
      #pragma unroll
      for (int n = 0; n < 4; ++n)
        #pragma unroll
        for (int i = 0; i < 4; ++i){
          const int scol = s0 + n * 16 + lr;
          const int qrow = q0 + w * 16 + lg * 4 + i;
          if (scol > qrow) sacc[n][i] = -__builtin_inff();
        }
    }
    float rmax[4], alpha[4], rsum[4];
    #pragma unroll
    for (int i = 0; i < 4; ++i){
      float v = fmaxf(fmaxf(sacc[0][i], sacc[1][i]), fmaxf(sacc[2][i], sacc[3][i]));
      v = fmaxf(v, __shfl_xor(v, 1));
      v = fmaxf(v, __shfl_xor(v, 2));
      v = fmaxf(v, __shfl_xor(v, 4));
      v = fmaxf(v, __shfl_xor(v, 8));
      rmax[i] = v;
    }
    #pragma unroll
    for (int i = 0; i < 4; ++i){
      const float mn = fmaxf(m_i[i], rmax[i]);
      alpha[i] = __expf(m_i[i] - mn);
      m_i[i] = mn;
      rsum[i] = 0.f;
    }
    #pragma unroll
    for (int n = 0; n < 4; ++n){
      #pragma unroll
      for (int i = 0; i < 4; ++i){
        const float pv = __expf(sacc[n][i] - m_i[i]);   // exp(-inf)=0 handles mask
        rsum[i] += pv;
        const int r = w * 16 + lg * 4 + i, c = n * 16 + lr;
        *(unsigned short*)((char*)Ps + (((r * 64 + c) * 2) ^ ((r & 7) << 4))) = f2bf(pv);
      }
    }
    #pragma unroll
    for (int i = 0; i < 4; ++i){
      float v = rsum[i];
      v += __shfl_xor(v, 1);
      v += __shfl_xor(v, 2);
      v += __shfl_xor(v, 4);
      v += __shfl_xor(v, 8);
      l_i[i] = l_i[i] * alpha[i] + v;
    }
    #pragma unroll
    for (int n = 0; n < 16; ++n)
      #pragma unroll
      for (int i = 0; i < 4; ++i) o_acc[n][i] *= alpha[i];
    // PV: each wave reads only its own P rows (same-wave LDS dep, compiler waits lgkmcnt)
    #pragma unroll
    for (int kc = 0; kc < 2; ++kc){
      const int r = w * 16 + lr, c = kc * 32 + lg * 8;
      bf16x8 pfr = *(const bf16x8*)((const char*)Ps + (((r * 64 + c) * 2) ^ ((r & 7) << 4)));
      #pragma unroll
      for (int n = 0; n < 16; ++n){
        const int vr = n * 16 + lr, vc = kc * 32 + lg * 8;
        bf16x8 vfr = *(const bf16x8*)((const char*)Vt + (((vr * 64 + vc) * 2) ^ ((vr & 7) << 4)));
        o_acc[n] = __builtin_amdgcn_mfma_f32_16x16x32_bf16(pfr, vfr, o_acc[n], 0, 0, 0);
      }
    }
  }
  #pragma unroll
  for (int n = 0; n < 16; ++n)
    #pragma unroll
    for (int i = 0; i < 4; ++i){
      const float v = o_acc[n][i] / l_i[i];
      const int q = q0 + w * 16 + lg * 4 + i;
      const int d = n * 16 + lr;
      ctxbf[(b * Tn + q) * Dn + d] = f2bf(v);
    }
}

// ---------------------------------------------------------------------------
// MLP: out = relu([H|ctx] @ W1^T + b1) @ W2^T + b2, fused per 64-row M tile.
// ---------------------------------------------------------------------------
__global__ __launch_bounds__(256, 1) void mlp_kernel(
    const unsigned short* __restrict__ Hbf, const unsigned short* __restrict__ ctxbf,
    const float* __restrict__ W1, const float* __restrict__ b1,
    const float* __restrict__ W2, const float* __restrict__ b2,
    float* __restrict__ out)
{
  const int m0 = blockIdx.x * 64;
  const int tid = threadIdx.x;
  const int w = tid >> 6, l = tid & 63;
  const int lr = l & 15, lg = l >> 4;

  __shared__ unsigned short As[64 * 512];
  __shared__ unsigned short Ws[64 * 512];

  {
    const int r = tid >> 2, cs = (tid & 3) * 128;
    #pragma unroll
    for (int jj = 0; jj < 16; ++jj){
      const int c = cs + jj * 8;
      u16x8 v;
      if (c < 256) v = *(const u16x8*)&Hbf[(m0 + r) * Dn + c];
      else         v = *(const u16x8*)&ctxbf[(m0 + r) * Dn + (c - 256)];
      *(u16x8*)((char*)As + (((r * 512 + c) * 2) ^ ((r & 7) << 4))) = v;
    }
  }
  f32x4 hacc[16];
  #pragma unroll
  for (int n = 0; n < 16; ++n) hacc[n] = (f32x4){0.f, 0.f, 0.f, 0.f};

  for (int nb = 0; nb < 4; ++nb){
    __syncthreads();
    {
      const int r = tid >> 2, cs = (tid & 3) * 128;
      #pragma unroll
      for (int jj = 0; jj < 32; ++jj){
        const int c = cs + jj * 4;
        const float4 v = *(const float4*)&W1[(nb * 64 + r) * 512 + c];
        u16x4 pk = { f2bf(v.x), f2bf(v.y), f2bf(v.z), f2bf(v.w) };
        *(u16x4*)((char*)Ws + (((r * 512 + c) * 2) ^ ((r & 7) << 4))) = pk;
      }
    }
    __syncthreads();
    #pragma unroll
    for (int kc = 0; kc < 16; ++kc){
      const int ar = w * 16 + lr, ac = kc * 32 + lg * 8;
      bf16x8 af = *(const bf16x8*)((const char*)As + (((ar * 512 + ac) * 2) ^ ((ar & 7) << 4)));
      #pragma unroll
      for (int n = 0; n < 4; ++n){
        const int br = n * 16 + lr;
        bf16x8 bf = *(const bf16x8*)((const char*)Ws + (((br * 512 + ac) * 2) ^ ((br & 7) << 4)));
        hacc[nb * 4 + n] = __builtin_amdgcn_mfma_f32_16x16x32_bf16(af, bf, hacc[nb * 4 + n], 0, 0, 0);
      }
    }
  }
  __syncthreads();
  // relu + b1 -> hid (bf16) into As as [64][256]
  #pragma unroll
  for (int nn = 0; nn < 16; ++nn){
    const int col = (nn >> 2) * 64 + (nn & 3) * 16 + lr;
    const float bv = b1[col];
    #pragma unroll
    for (int i = 0; i < 4; ++i){
      float v = hacc[nn][i] + bv;
      v = v > 0.f ? v : 0.f;
      const int r = w * 16 + lg * 4 + i;
      *(unsigned short*)((char*)As + (((r * 256 + col) * 2) ^ ((r & 7) << 4))) = f2bf(v);
    }
  }
  {
    const int r = tid >> 2, cs = (tid & 3) * 64;
    #pragma unroll
    for (int jj = 0; jj < 16; ++jj){
      const int c = cs + jj * 4;
      const float4 v = *(const float4*)&W2[r * 256 + c];
      u16x4 pk = { f2bf(v.x), f2bf(v.y), f2bf(v.z), f2bf(v.w) };
      *(u16x4*)((char*)Ws + (((r * 256 + c) * 2) ^ ((r & 7) << 4))) = pk;
    }
  }
  __syncthreads();
  f32x4 oacc[4];
  #pragma unroll
  for (int n = 0; n < 4; ++n) oacc[n] = (f32x4){0.f, 0.f, 0.f, 0.f};
  #pragma unroll
  for (int kc = 0; kc < 8; ++kc){
    const int ar = w * 16 + lr, ac = kc * 32 + lg * 8;
    bf16x8 af = *(const bf16x8*)((const char*)As + (((ar * 256 + ac) * 2) ^ ((ar & 7) << 4)));
    #pragma unroll
    for (int n = 0; n < 4; ++n){
      const int br = n * 16 + lr;
      bf16x8 bf = *(const bf16x8*)((const char*)Ws + (((br * 256 + ac) * 2) ^ ((br & 7) << 4)));
      oacc[n] = __builtin_amdgcn_mfma_f32_16x16x32_bf16(af, bf, oacc[n], 0, 0, 0);
    }
  }
  #pragma unroll
  for (int n = 0; n < 4; ++n)
    #pragma unroll
    for (int i = 0; i < 4; ++i){
      const int ii = n * 16 + lr;
      const int m = m0 + w * 16 + lg * 4 + i;
      out[m * In + ii] = oacc[n][i] + b2[ii];
    }
}

extern "C" void kernel_launch(void* const* d_in, const int* in_sizes, int n_in,
                              void* d_out, int out_size, void* d_ws, size_t ws_size,
                              hipStream_t stream)
{
  (void)in_sizes; (void)n_in; (void)out_size; (void)ws_size;
  const float* x   = (const float*)d_in[0];
  const float* Wih = (const float*)d_in[1];
  const float* Whh = (const float*)d_in[2];
  const float* bih = (const float*)d_in[3];
  const float* bhh = (const float*)d_in[4];
  const float* W1  = (const float*)d_in[5];
  const float* b1  = (const float*)d_in[6];
  const float* W2  = (const float*)d_in[7];
  const float* b2  = (const float*)d_in[8];
  float* out = (float*)d_out;

  char* ws = (char*)d_ws;
  unsigned short* Hbf   = (unsigned short*)ws;                              // 32 MB
  unsigned short* ctxbf = (unsigned short*)(ws + (size_t)32 * 1024 * 1024); // 32 MB
  unsigned short* hx    = (unsigned short*)(ws + (size_t)64 * 1024 * 1024); // 64 KB
  unsigned int*   tags  = (unsigned int*)(ws + (size_t)64 * 1024 * 1024 + 128 * 1024); // 512 B

  hipMemsetAsync(tags, 0, 2 * 64 * sizeof(unsigned int), stream);
  lstm_scan_kernel<<<16, 256, 0, stream>>>(x, Wih, Whh, bih, bhh, Hbf, hx, tags);
  attn_kernel<<<Bn * 16, 256, 0, stream>>>(Hbf, ctxbf);
  mlp_kernel<<<(Bn * Tn) / 64, 256, 0, stream>>>(Hbf, ctxbf, W1, b1, W2, b2, out);
}